// Round 13
// baseline (124.439 us; speedup 1.0000x reference)
//
#include <hip/hip_runtime.h>
#include <math.h>

// VQ-VAE vector quantizer for MI355X (gfx950).
// z: [32768, 64] fp32, codebook: [1024, 64] fp32.
// Outputs (flat float32, concatenated): quantized_st [32768*64], vq_loss [1],
// indices [32768] (as float), perplexity [1].
//
// R13: R12 bisection: pure K-loop (vq_score) is ~35 us, ~85% idle, invariant
// to data path. Last untested lever: occupancy WITHOUT changing register
// allocation. R12's score (~124 VGPR) already fits 4 waves/SIMD; the grid
// (512 blocks = 2048 waves) was the cap. R13: each score block does 64 rows
// x HALF the codes (512) -> 1024 blocks = 4096 waves = 4/SIMD, identical
// kernel body + pressure; writer merges the two halves' top-2 (exact) and
// rechecks. If score doesn't drop, the occupancy theory is finally dead.
// Numerics unchanged: 3-term split-bf16 + exact fp32 recheck (margin 1e-5).

#define D 64
#define KC 1024
#define MT 4              // 16-row m-tiles per wave
#define ROWS (MT * 16)    // 64 rows per block

typedef short short8 __attribute__((ext_vector_type(8)));
typedef short short4v __attribute__((ext_vector_type(4)));
typedef float f32x4 __attribute__((ext_vector_type(4)));

__device__ __forceinline__ unsigned short f2bf(float x) {
  unsigned int u = __float_as_uint(x);
  unsigned int r = (u + 0x7fffu + ((u >> 16) & 1u)) >> 16;
  return (unsigned short)r;
}
__device__ __forceinline__ float bf2f(unsigned short h) {
  return __uint_as_float((unsigned int)h << 16);
}

// blocks 0..3: codebook norms + split-bf16 bsplit[k][128]=[e_hi|e_lo],
//              zero hist/loss.
// blocks 4..515: z rows -> zsplit[row][128]=[z_hi|z_lo] + rzn[row]=||z||^2.
__global__ __launch_bounds__(256) void vq_prep(
    const float* __restrict__ cb, const float* __restrict__ z,
    unsigned short* __restrict__ bsplit, unsigned short* __restrict__ zsplit,
    float* __restrict__ cbn, float* __restrict__ rzn,
    unsigned int* __restrict__ hist, float* __restrict__ loss_acc) {
  __shared__ float srzp[1024];
  const int b = blockIdx.x;
  const int tid = threadIdx.x;
  if (b < 4) {
    const int k = b * 256 + tid;  // 0..1023
    const float4* e = (const float4*)(cb + (size_t)k * D);
    unsigned short* bp = bsplit + (size_t)k * 128;
    float s0 = 0.f, s1 = 0.f, s2 = 0.f, s3 = 0.f;
#pragma unroll
    for (int i = 0; i < 16; ++i) {
      float4 v = e[i];
      s0 = fmaf(v.x, v.x, s0);
      s1 = fmaf(v.y, v.y, s1);
      s2 = fmaf(v.z, v.z, s2);
      s3 = fmaf(v.w, v.w, s3);
      unsigned short h0 = f2bf(v.x), h1 = f2bf(v.y), h2 = f2bf(v.z),
                     h3 = f2bf(v.w);
      short4v hv = {(short)h0, (short)h1, (short)h2, (short)h3};
      short4v lv = {(short)f2bf(v.x - bf2f(h0)), (short)f2bf(v.y - bf2f(h1)),
                    (short)f2bf(v.z - bf2f(h2)), (short)f2bf(v.w - bf2f(h3))};
      *(short4v*)(bp + i * 4) = hv;
      *(short4v*)(bp + 64 + i * 4) = lv;
    }
    cbn[k] = (s0 + s1) + (s2 + s3);
    hist[k] = 0u;
    if (k == 0) loss_acc[0] = 0.f;
  } else {
    const int rowbase = (b - 4) * 64;
    const float4* z4 = (const float4*)(z + (size_t)rowbase * D);
#pragma unroll
    for (int it = 0; it < 4; ++it) {
      int f4 = it * 256 + tid;  // row*16 + (c4/4)
      int row = f4 >> 4, c4 = (f4 & 15) * 4;
      float4 v = z4[f4];
      srzp[f4] = ((v.x * v.x + v.y * v.y) + (v.z * v.z + v.w * v.w));
      unsigned short h0 = f2bf(v.x), h1 = f2bf(v.y), h2 = f2bf(v.z),
                     h3 = f2bf(v.w);
      short4v hv = {(short)h0, (short)h1, (short)h2, (short)h3};
      short4v lv = {(short)f2bf(v.x - bf2f(h0)), (short)f2bf(v.y - bf2f(h1)),
                    (short)f2bf(v.z - bf2f(h2)), (short)f2bf(v.w - bf2f(h3))};
      unsigned short* zp = zsplit + (size_t)(rowbase + row) * 128;
      *(short4v*)(zp + c4) = hv;
      *(short4v*)(zp + 64 + c4) = lv;
    }
    __syncthreads();
    if (tid < 64) {
      float s = 0.f;
#pragma unroll
      for (int i = 0; i < 16; ++i) s += srzp[tid * 16 + i];
      rzn[rowbase + tid] = s;
    }
  }
}

// Pure K-loop, half the codebook per block: block = (rowblk, half).
// 1024 blocks x 4 waves = 4096 waves = 4 waves/SIMD at unchanged ~124 VGPR.
__global__ __launch_bounds__(256, 2) void vq_score(
    const unsigned short* __restrict__ zsplit, const float* __restrict__ rzn,
    const unsigned short* __restrict__ bsplit, const float* __restrict__ cbn,
    float* __restrict__ t2d, int* __restrict__ t2k) {
  __shared__ float candd[4][ROWS][17];  // +1 pad
  __shared__ int candk[4][ROWS][17];

  const int tid = threadIdx.x;
  const int lane = tid & 63;
  const int wav = tid >> 6;
  const int quad = lane >> 4;
  const int col = lane & 15;
  const int half = blockIdx.x & 1;
  const int rowbase = (blockIdx.x >> 1) * ROWS;

  // A fragments from global zsplit: lane holds A[m=col][k=quad*8+j].
  short8 a[MT][4];
#pragma unroll
  for (int mt = 0; mt < MT; ++mt) {
    const unsigned short* base =
        zsplit + (size_t)(rowbase + mt * 16 + col) * 128 + quad * 8;
    a[mt][0] = *(const short8*)(base + 0);    // z_hi k 0..31
    a[mt][1] = *(const short8*)(base + 32);   // z_hi k 32..63
    a[mt][2] = *(const short8*)(base + 64);   // z_lo k 0..31
    a[mt][3] = *(const short8*)(base + 96);   // z_lo k 32..63
  }
  float rzv[MT * 4];
#pragma unroll
  for (int mt = 0; mt < MT; ++mt)
#pragma unroll
    for (int reg = 0; reg < 4; ++reg)
      rzv[mt * 4 + reg] = rzn[rowbase + mt * 16 + quad * 4 + reg];

  float bestd[MT * 4];
  int bestk[MT * 4];
#pragma unroll
  for (int i = 0; i < MT * 4; ++i) {
    bestd[i] = 3.4e38f;
    bestk[i] = 0;
  }

  // 4 iterations x 2 sub-tiles of 16 codes (128 codes per wave),
  // distance-2 register prefetch. Body identical to R12's.
  const int k0 = half * 512 + wav * 128;
  short8 p0[4], p1[4];
  float pe0, pe1;
  {
    const unsigned short* b0p = bsplit + (size_t)(k0 + col) * 128 + quad * 8;
    p0[0] = *(const short8*)(b0p + 0);
    p0[1] = *(const short8*)(b0p + 32);
    p0[2] = *(const short8*)(b0p + 64);
    p0[3] = *(const short8*)(b0p + 96);
    pe0 = cbn[k0 + col];
    const unsigned short* b1p =
        bsplit + (size_t)(k0 + 16 + col) * 128 + quad * 8;
    p1[0] = *(const short8*)(b1p + 0);
    p1[1] = *(const short8*)(b1p + 32);
    p1[2] = *(const short8*)(b1p + 64);
    p1[3] = *(const short8*)(b1p + 96);
    pe1 = cbn[k0 + 16 + col];
  }

  for (int it = 0; it < 4; ++it) {
    const short8 c00 = p0[0], c01 = p0[1], c02 = p0[2], c03 = p0[3];
    const short8 c10 = p1[0], c11 = p1[1], c12 = p1[2], c13 = p1[3];
    const float ce0 = pe0, ce1 = pe1;
    const int kbase = k0 + it * 32;
    if (it < 3) {
      const unsigned short* n0 =
          bsplit + (size_t)(kbase + 32 + col) * 128 + quad * 8;
      p0[0] = *(const short8*)(n0 + 0);
      p0[1] = *(const short8*)(n0 + 32);
      p0[2] = *(const short8*)(n0 + 64);
      p0[3] = *(const short8*)(n0 + 96);
      pe0 = cbn[kbase + 32 + col];
      const unsigned short* n1 =
          bsplit + (size_t)(kbase + 48 + col) * 128 + quad * 8;
      p1[0] = *(const short8*)(n1 + 0);
      p1[1] = *(const short8*)(n1 + 32);
      p1[2] = *(const short8*)(n1 + 64);
      p1[3] = *(const short8*)(n1 + 96);
      pe1 = cbn[kbase + 48 + col];
    }
    {
      f32x4 acc[MT];
#pragma unroll
      for (int mt = 0; mt < MT; ++mt) acc[mt] = {0.f, 0.f, 0.f, 0.f};
#pragma unroll
      for (int mt = 0; mt < MT; ++mt)
        acc[mt] = __builtin_amdgcn_mfma_f32_16x16x32_bf16(a[mt][0], c00, acc[mt], 0, 0, 0);
#pragma unroll
      for (int mt = 0; mt < MT; ++mt)
        acc[mt] = __builtin_amdgcn_mfma_f32_16x16x32_bf16(a[mt][1], c01, acc[mt], 0, 0, 0);
#pragma unroll
      for (int mt = 0; mt < MT; ++mt)
        acc[mt] = __builtin_amdgcn_mfma_f32_16x16x32_bf16(a[mt][2], c00, acc[mt], 0, 0, 0);
#pragma unroll
      for (int mt = 0; mt < MT; ++mt)
        acc[mt] = __builtin_amdgcn_mfma_f32_16x16x32_bf16(a[mt][3], c01, acc[mt], 0, 0, 0);
#pragma unroll
      for (int mt = 0; mt < MT; ++mt)
        acc[mt] = __builtin_amdgcn_mfma_f32_16x16x32_bf16(a[mt][0], c02, acc[mt], 0, 0, 0);
#pragma unroll
      for (int mt = 0; mt < MT; ++mt)
        acc[mt] = __builtin_amdgcn_mfma_f32_16x16x32_bf16(a[mt][1], c03, acc[mt], 0, 0, 0);
      const int mycode = kbase + col;
#pragma unroll
      for (int mt = 0; mt < MT; ++mt)
#pragma unroll
        for (int reg = 0; reg < 4; ++reg) {
          float dist = fmaf(-2.0f, acc[mt][reg], rzv[mt * 4 + reg] + ce0);
          int i = mt * 4 + reg;
          bool better = dist < bestd[i];
          bestk[i] = better ? mycode : bestk[i];
          bestd[i] = better ? dist : bestd[i];
        }
    }
    {
      f32x4 acc[MT];
#pragma unroll
      for (int mt = 0; mt < MT; ++mt) acc[mt] = {0.f, 0.f, 0.f, 0.f};
#pragma unroll
      for (int mt = 0; mt < MT; ++mt)
        acc[mt] = __builtin_amdgcn_mfma_f32_16x16x32_bf16(a[mt][0], c10, acc[mt], 0, 0, 0);
#pragma unroll
      for (int mt = 0; mt < MT; ++mt)
        acc[mt] = __builtin_amdgcn_mfma_f32_16x16x32_bf16(a[mt][1], c11, acc[mt], 0, 0, 0);
#pragma unroll
      for (int mt = 0; mt < MT; ++mt)
        acc[mt] = __builtin_amdgcn_mfma_f32_16x16x32_bf16(a[mt][2], c10, acc[mt], 0, 0, 0);
#pragma unroll
      for (int mt = 0; mt < MT; ++mt)
        acc[mt] = __builtin_amdgcn_mfma_f32_16x16x32_bf16(a[mt][3], c11, acc[mt], 0, 0, 0);
#pragma unroll
      for (int mt = 0; mt < MT; ++mt)
        acc[mt] = __builtin_amdgcn_mfma_f32_16x16x32_bf16(a[mt][0], c12, acc[mt], 0, 0, 0);
#pragma unroll
      for (int mt = 0; mt < MT; ++mt)
        acc[mt] = __builtin_amdgcn_mfma_f32_16x16x32_bf16(a[mt][1], c13, acc[mt], 0, 0, 0);
      const int mycode = kbase + 16 + col;
#pragma unroll
      for (int mt = 0; mt < MT; ++mt)
#pragma unroll
        for (int reg = 0; reg < 4; ++reg) {
          float dist = fmaf(-2.0f, acc[mt][reg], rzv[mt * 4 + reg] + ce1);
          int i = mt * 4 + reg;
          bool better = dist < bestd[i];
          bestk[i] = better ? mycode : bestk[i];
          bestd[i] = better ? dist : bestd[i];
        }
    }
  }

  // publish per-lane candidates: per row, 16 col-classes x 4 waves
#pragma unroll
  for (int mt = 0; mt < MT; ++mt)
#pragma unroll
    for (int reg = 0; reg < 4; ++reg) {
      int row = mt * 16 + quad * 4 + reg;
      candd[wav][row][col] = bestd[mt * 4 + reg];
      candk[wav][row][col] = bestk[mt * 4 + reg];
    }
  __syncthreads();

  // per-row exact top-2 of the 64 candidates -> ws[row][half]
  if (tid < ROWS) {
    float bd1 = 3.4e38f, bd2 = 3.4e38f;
    int bk1 = 0x7fffffff, bk2 = 0x7fffffff;
#pragma unroll
    for (int w = 0; w < 4; ++w)
      for (int c = 0; c < 16; ++c) {
        float dv = candd[w][tid][c];
        int kv = candk[w][tid][c];
        bool h1 = (dv < bd1) || (dv == bd1 && kv < bk1);
        bool h2 = (dv < bd2) || (dv == bd2 && kv < bk2);
        if (h1) {
          bd2 = bd1; bk2 = bk1;
          bd1 = dv; bk1 = kv;
        } else if (h2) {
          bd2 = dv; bk2 = kv;
        }
      }
    const int row = rowbase + tid;
    t2d[row * 4 + half * 2] = bd1;
    t2d[row * 4 + half * 2 + 1] = bd2;
    t2k[row * 4 + half * 2] = bk1;
    t2k[row * 4 + half * 2 + 1] = bk2;
  }
}

// merge halves + recheck + idx + dedup hist + quantized gather-write + loss
__global__ __launch_bounds__(256) void vq_writer(
    const float* __restrict__ z, const float* __restrict__ cb,
    const float* __restrict__ cbn, const float* __restrict__ t2d,
    const int* __restrict__ t2k, float* __restrict__ out_q,
    float* __restrict__ out_idx, unsigned int* __restrict__ hist,
    float* __restrict__ loss_acc) {
  __shared__ int skf[ROWS];
  __shared__ unsigned int lhist[KC];
  __shared__ float swav[4];
  const int tid = threadIdx.x;
  const int lane = tid & 63;
  const int wav = tid >> 6;
  const int rowbase = blockIdx.x * ROWS;

#pragma unroll
  for (int j = 0; j < KC / 256; ++j) lhist[tid + 256 * j] = 0u;
  __syncthreads();

  if (tid < ROWS) {
    const int row = rowbase + tid;
    const float4 dv = *(const float4*)&t2d[row * 4];  // d1h0,d2h0,d1h1,d2h1
    const int4 kv = *(const int4*)&t2k[row * 4];
    float cd[4] = {dv.x, dv.y, dv.z, dv.w};
    int ck[4] = {kv.x, kv.y, kv.z, kv.w};
    float bd1 = 3.4e38f, bd2 = 3.4e38f;
    int bk1 = 0x7fffffff, bk2 = 0x7fffffff;
#pragma unroll
    for (int c = 0; c < 4; ++c) {
      bool h1 = (cd[c] < bd1) || (cd[c] == bd1 && ck[c] < bk1);
      bool h2 = (cd[c] < bd2) || (cd[c] == bd2 && ck[c] < bk2);
      if (h1) {
        bd2 = bd1; bk2 = bk1;
        bd1 = cd[c]; bk1 = ck[c];
      } else if (h2) {
        bd2 = cd[c]; bk2 = ck[c];
      }
    }
    if (bd2 - bd1 < 1e-5f) {
      // exact fp32 recompute (R3 arithmetic) of the top-2 candidates
      const float4* zp = (const float4*)(z + (size_t)row * D);
      float s0 = 0.f, s1 = 0.f, s2 = 0.f, s3 = 0.f;
#pragma unroll
      for (int i = 0; i < 16; ++i) {
        float4 v = zp[i];
        s0 = fmaf(v.x, v.x, s0);
        s1 = fmaf(v.y, v.y, s1);
        s2 = fmaf(v.z, v.z, s2);
        s3 = fmaf(v.w, v.w, s3);
      }
      const float rzx = (s0 + s1) + (s2 + s3);
      float dx[2];
      int kk[2] = {bk1, bk2};
#pragma unroll
      for (int c = 0; c < 2; ++c) {
        const float4* e4 = (const float4*)(cb + (size_t)kk[c] * D);
        float d0 = 0.f, d1 = 0.f, d2 = 0.f, d3 = 0.f;
#pragma unroll
        for (int i = 0; i < 16; ++i) {
          float4 v = e4[i];
          float4 zv = zp[i];
          d0 = fmaf(zv.x, v.x, d0);
          d1 = fmaf(zv.y, v.y, d1);
          d2 = fmaf(zv.z, v.z, d2);
          d3 = fmaf(zv.w, v.w, d3);
        }
        float dot = (d0 + d1) + (d2 + d3);
        dx[c] = (rzx + cbn[kk[c]]) - 2.0f * dot;
      }
      if ((dx[1] < dx[0]) || (dx[1] == dx[0] && bk2 < bk1)) bk1 = bk2;
    }
    skf[tid] = bk1;
    out_idx[row] = (float)bk1;
    atomicAdd(&lhist[bk1], 1u);
  }
  __syncthreads();

#pragma unroll
  for (int j = 0; j < KC / 256; ++j) {
    unsigned int c = lhist[tid + 256 * j];
    if (c) atomicAdd(&hist[tid + 256 * j], c);
  }

  float lsum = 0.f;
#pragma unroll
  for (int it = 0; it < 4; ++it) {
    int f4 = it * 256 + tid;
    int r = f4 >> 4;
    int c4 = (f4 & 15) * 4;
    int bk = skf[r];
    const float4 q = *(const float4*)(cb + (size_t)bk * D + c4);
    const int grow = rowbase + r;
    const float4 zv = *(const float4*)(z + (size_t)grow * D + c4);
    *(float4*)(out_q + (size_t)grow * D + c4) = q;
    float ax = q.x - zv.x, ay = q.y - zv.y, az = q.z - zv.z, aw = q.w - zv.w;
    lsum += ax * ax + ay * ay + az * az + aw * aw;
  }
#pragma unroll
  for (int off = 32; off > 0; off >>= 1) lsum += __shfl_down(lsum, off, 64);
  if (lane == 0) swav[wav] = lsum;
  __syncthreads();
  if (tid == 0)
    atomicAdd(loss_acc, (swav[0] + swav[1]) + (swav[2] + swav[3]));
}

__global__ __launch_bounds__(1024) void vq_final(
    const unsigned int* __restrict__ hist, const float* __restrict__ loss_acc,
    float* __restrict__ out_loss, float* __restrict__ out_perp, float inv_n,
    float inv_nd) {
  __shared__ float part[16];
  const int t = threadIdx.x;
  const int lane = t & 63;
  const int wav = t >> 6;
  float p = (float)hist[t] * inv_n;
  float v = p * logf(p + 1e-10f);
#pragma unroll
  for (int off = 32; off > 0; off >>= 1) v += __shfl_down(v, off, 64);
  if (lane == 0) part[wav] = v;
  __syncthreads();
  if (t == 0) {
    float s = 0.f;
#pragma unroll
    for (int j = 0; j < 16; ++j) s += part[j];
    *out_perp = expf(-s);
    // q_latent + 0.25*e_latent, both numerically mean((q-z)^2)
    *out_loss = 1.25f * loss_acc[0] * inv_nd;
  }
}

extern "C" void kernel_launch(void* const* d_in, const int* in_sizes, int n_in,
                              void* d_out, int out_size, void* d_ws,
                              size_t ws_size, hipStream_t stream) {
  (void)n_in;
  (void)out_size;
  (void)ws_size;
  const float* z = (const float*)d_in[0];
  const float* cb = (const float*)d_in[1];
  const int N = in_sizes[0] / D;  // 32768

  // Output layout (flat float32, reference return order):
  float* out_q = (float*)d_out;                     // N*D
  float* out_loss = (float*)d_out + (size_t)N * D;  // 1
  float* out_idx = out_loss + 1;                    // N
  float* out_perp = out_idx + N;                    // 1

  // Workspace (float indices): hist[1024]u32 @0, loss @1024, cbn @1040,
  // bsplit short[131072] @2064, zsplit short[4194304] @67600,
  // rzn[32768] @2164752, t2d float[131072] @2197520,
  // t2k int[131072] @2328592.
  unsigned int* hist = (unsigned int*)d_ws;
  float* loss_acc = (float*)d_ws + 1024;
  float* cbn = (float*)d_ws + 1040;
  unsigned short* bsplit = (unsigned short*)((float*)d_ws + 2064);
  unsigned short* zsplit = (unsigned short*)((float*)d_ws + 67600);
  float* rzn = (float*)d_ws + 2164752;
  float* t2d = (float*)d_ws + 2197520;
  int* t2k = (int*)((float*)d_ws + 2328592);

  vq_prep<<<dim3(4 + N / 64), dim3(256), 0, stream>>>(cb, z, bsplit, zsplit,
                                                      cbn, rzn, hist, loss_acc);
  vq_score<<<dim3(2 * (N / ROWS)), dim3(256), 0, stream>>>(zsplit, rzn, bsplit,
                                                           cbn, t2d, t2k);
  vq_writer<<<dim3(N / ROWS), dim3(256), 0, stream>>>(
      z, cb, cbn, t2d, t2k, out_q, out_idx, hist, loss_acc);
  vq_final<<<dim3(1), dim3(1024), 0, stream>>>(
      hist, loss_acc, out_loss, out_perp, 1.0f / (float)N,
      1.0f / ((float)N * (float)D));
}